// Round 14
// baseline (410.921 us; speedup 1.0000x reference)
//
#include <hip/hip_runtime.h>

#define N_NODES 81920
#define N_EDGES 1310720
#define NG 256
#define D 64
#define TM 64
#define SA 65            // f32 LDS row stride (GEMM tiles)
#define SB 33            // bf16x2 LDS row stride in push (2-way bank alias, free)
#define NB 320           // 256-thread node blocks covering N_NODES
#define NBLK 1280        // src blocks of 64 nodes
#define BMW 2560         // bitmask words (81920/32)
#define HCHUNK 4096      // edges per build workgroup (NB*HCHUNK == N_EDGES)
#define EPT 16           // edges per thread in build
#define CAP0 1280        // slab capacities per src block (mean 576, sigma 24)
#define CAP1 256
#define CAP2 64

typedef __attribute__((ext_vector_type(2))) short sbf2;

__device__ __forceinline__ bool tb(const unsigned* bm, int i) {
    return (bm[i >> 5] >> (i & 31)) & 1u;
}
__device__ __forceinline__ unsigned bf16rne(float f) {
    unsigned u = __float_as_uint(f);
    return (u + 0x7fffu + ((u >> 16) & 1u)) >> 16;
}

// ---------------- graph firsts + seed bm2/bm1 + zero aggf rows + cursor init --------

__global__ void ff_mark(const int* __restrict__ batch, int* __restrict__ fidx,
                        unsigned* __restrict__ bm2, unsigned* __restrict__ bm1,
                        float* __restrict__ aggf,
                        int* __restrict__ cur0, int* __restrict__ cur1,
                        int* __restrict__ cur2) {
    int i = blockIdx.x * 256 + threadIdx.x;          // grid NB
    if (i < NBLK) {                                  // slab cursor init
        cur0[i] = i * CAP0; cur1[i] = i * CAP1; cur2[i] = i * CAP2;
    }
    int b = batch[i];
    if (i == 0 || batch[i - 1] != b) {
        fidx[b] = i;
        unsigned bit = 1u << (i & 31);
        atomicOr(&bm2[i >> 5], bit);
        atomicOr(&bm1[i >> 5], bit);
        float4* r = (float4*)&aggf[i * D];           // zero this output row (layer-2 agg)
        #pragma unroll
        for (int j = 0; j < 16; ++j) r[j] = make_float4(0.f, 0.f, 0.f, 0.f);
    }
}

// mark srcs of edges with dst-bit in bmD into bmS; optional OR-copy orsrc -> bmS
__global__ void mark_srcs_bm(const int* __restrict__ src, const int* __restrict__ dst,
                             const unsigned* __restrict__ bmD, unsigned* __restrict__ bmS,
                             const unsigned* __restrict__ orsrc) {
    if (orsrc && blockIdx.x == 0) {
        for (int w = threadIdx.x; w < BMW; w += 256)
            if (orsrc[w]) atomicOr(&bmS[w], orsrc[w]);
    }
    int e = blockIdx.x * 256 + threadIdx.x;
    if (e < N_EDGES && tb(bmD, dst[e])) {
        int s = src[e];
        atomicOr(&bmS[s >> 5], 1u << (s & 31));
    }
}

// ---------------- build: ONE edge stream, register-carried ranks, slab bucketing ----

__global__ __launch_bounds__(256) void build(const int* __restrict__ src,
                                             const int* __restrict__ dst,
                                             const unsigned* __restrict__ bm0,
                                             const unsigned* __restrict__ bm1,
                                             const unsigned* __restrict__ bm2,
                                             int* __restrict__ cur0,
                                             int* __restrict__ cur1,
                                             int* __restrict__ cur2,
                                             int* __restrict__ esp0,
                                             int* __restrict__ esp1,
                                             int* __restrict__ esp2,
                                             int* __restrict__ indeg,
                                             int* __restrict__ list1,
                                             int* __restrict__ n1) {
    __shared__ int h0[NBLK];
    __shared__ int b0[NBLK];
    const int tid = threadIdx.x;
    const int e0  = blockIdx.x * HCHUNK;             // grid NB (320)

    for (int i = tid; i < NBLK; i += 256) h0[i] = 0;

    // list1 compaction for this WG's 256-node chunk
    {
        int i = blockIdx.x * 256 + tid;
        int lane = tid & 63;
        bool p1 = tb(bm1, i);
        unsigned long long b1 = __ballot(p1);
        int lt = __popcll(b1 & ((1ull << lane) - 1));
        int base = 0;
        if (lane == 0 && b1) base = atomicAdd(n1, __popcll(b1));
        base = __shfl(base, 0);
        if (p1) list1[base + lt] = i;
    }
    __syncthreads();

    int pk_r[EPT], sb_r[EPT], rk_r[EPT];

    #pragma unroll
    for (int j = 0; j < EPT; ++j) {
        int e = e0 + j * 256 + tid;                  // coalesced
        int d = dst[e];
        sb_r[j] = -1;
        if (tb(bm0, d)) {
            int s  = src[e];
            int sb = s >> 6;
            int pk = (d << 6) | (s & 63);
            pk_r[j] = pk;
            sb_r[j] = sb;
            rk_r[j] = atomicAdd(&h0[sb], 1);         // LDS
            atomicAdd(&indeg[d], 1);                 // global fire-and-forget
            if (tb(bm1, d)) {
                int p1 = atomicAdd(&cur1[sb], 1);    // rare (9%)
                if (p1 < sb * CAP1 + CAP1) esp1[p1] = pk;
                if (tb(bm2, d)) {
                    int p2 = atomicAdd(&cur2[sb], 1); // very rare (0.7%)
                    if (p2 < sb * CAP2 + CAP2) esp2[p2] = pk;
                }
            }
        }
    }
    __syncthreads();

    for (int i = tid; i < NBLK; i += 256) {
        int c = h0[i];
        b0[i] = c ? atomicAdd(&cur0[i], c) : 0;
    }
    __syncthreads();

    #pragma unroll
    for (int j = 0; j < EPT; ++j) {
        int sb = sb_r[j];
        if (sb >= 0) {
            int pos = b0[sb] + rk_r[j];
            if (pos < sb * CAP0 + CAP0) esp0[pos] = pk_r[j];
        }
    }
}

// ---------------- push (bf16x2 pk atomics): 128 B/edge, 2 edges per wave-step ----

__global__ __launch_bounds__(256, 8) void sage_push_bf(
    const float* __restrict__ hin, const int* __restrict__ cur,
    const int* __restrict__ esp, unsigned* __restrict__ aggb, int cap)
{
    __shared__ unsigned Rs[TM * SB];  // 64 src rows, pre-packed bf16x2

    const int tid  = threadIdx.x;
    const int base = blockIdx.x * TM;
    const int lane = tid & 63;
    const int w    = tid >> 6;
    const int l5   = lane & 31;
    const int hi   = lane >> 5;

    const int e0 = blockIdx.x * cap;
    const int e1 = min(cur[blockIdx.x], e0 + cap);
    if (e0 == e1) return;

    for (int idx = tid; idx < TM * 32; idx += 256) {
        int m = idx >> 5, k = idx & 31;
        float2 v = *(const float2*)&hin[((base + m) << 6) + (k << 1)];
        Rs[m * SB + k] = bf16rne(v.x) | (bf16rne(v.y) << 16);
    }
    __syncthreads();

    const int chunk = ((e1 - e0) + 3) >> 2;
    int e = e0 + w * chunk;
    const int ee = min(e + chunk, e1);

    for (; e + 64 <= ee; e += 64) {
        int pv = esp[e + lane];
        #pragma unroll
        for (int u = 0; u < 32; ++u) {
            int p = __shfl(pv, (u << 1) + hi);
            unsigned v = Rs[(p & 63) * SB + l5];
            __builtin_amdgcn_global_atomic_fadd_v2bf16(
                (sbf2*)&aggb[((p >> 6) << 5) + l5], *(sbf2*)&v);
        }
    }
    for (; e < ee; ++e) {
        int p = esp[e];
        if (!hi) {
            unsigned v = Rs[(p & 63) * SB + l5];
            __builtin_amdgcn_global_atomic_fadd_v2bf16(
                (sbf2*)&aggb[((p >> 6) << 5) + l5], *(sbf2*)&v);
        }
    }
}

// ---------------- push (f32, exact): layer 2 into aggf ----------------

__global__ __launch_bounds__(256, 8) void sage_push_f32(
    const float* __restrict__ hin, const int* __restrict__ cur,
    const int* __restrict__ esp, float* __restrict__ agg, int cap)
{
    __shared__ float Rs[TM * SA];

    const int tid  = threadIdx.x;
    const int base = blockIdx.x * TM;
    const int lane = tid & 63;
    const int w    = tid >> 6;

    const int e0 = blockIdx.x * cap;
    const int e1 = min(cur[blockIdx.x], e0 + cap);
    if (e0 == e1) return;

    for (int idx = tid; idx < TM * D; idx += 256) {
        int m = idx >> 6, k = idx & 63;
        Rs[m * SA + k] = hin[(base << 6) + idx];
    }
    __syncthreads();

    const int chunk = ((e1 - e0) + 3) >> 2;
    int e = e0 + w * chunk;
    const int ee = min(e + chunk, e1);

    for (; e < ee; ++e) {
        int p = esp[e];
        atomicAdd(&agg[(p & 0x7fffffc0) + lane], Rs[(p & 63) * SA + lane]);
    }
}

// ---------------- FUSED: dense finish L0 + push L1 (ping-pong aggbA -> aggbB) -------

__global__ __launch_bounds__(256, 4) void finish_dense_push1(
    const float* __restrict__ hin, const unsigned* __restrict__ aggbA,
    const int* __restrict__ indeg, float* __restrict__ hout,
    const float* __restrict__ Wl, const float* __restrict__ bl,
    const float* __restrict__ Wr,
    const int* __restrict__ cur1, const int* __restrict__ esp1,
    unsigned* __restrict__ aggbB)
{
    __shared__ float As[TM * SA];
    __shared__ float Xs[TM * SA];
    __shared__ float invs[TM];

    const int tid  = threadIdx.x;
    const int t    = blockIdx.x;                     // grid NBLK
    const int base = t * TM;

    if (tid < TM) invs[tid] = 1.0f / (float)max(indeg[base + tid], 1);
    for (int idx = tid; idx < TM * 32; idx += 256) { // unpack bf16x2 agg (no re-zero)
        int m = idx >> 5, k2 = idx & 31;
        unsigned v = aggbA[(base << 5) + idx];
        As[m * SA + (k2 << 1)]     = __uint_as_float(v << 16);
        As[m * SA + (k2 << 1) + 1] = __uint_as_float(v & 0xffff0000u);
    }
    for (int idx = tid; idx < TM * D; idx += 256) {
        int m = idx >> 6, k = idx & 63;
        Xs[m * SA + k] = hin[(base << 6) + idx];     // coalesced stream
    }
    __syncthreads();
    for (int idx = tid; idx < TM * D; idx += 256) {
        int m = idx >> 6, k = idx & 63;
        As[m * SA + k] *= invs[m];
    }
    __syncthreads();

    const int j0 = (tid & 15) << 2;
    const int m0 = (tid >> 4) << 2;
    float o[4][4];
    float4 b4 = *(const float4*)&bl[j0];
    #pragma unroll
    for (int mi = 0; mi < 4; ++mi) {
        o[mi][0] = b4.x; o[mi][1] = b4.y; o[mi][2] = b4.z; o[mi][3] = b4.w;
    }
    #pragma unroll 8
    for (int k = 0; k < D; ++k) {
        float4 wl = *(const float4*)&Wl[(k << 6) + j0];
        float4 wr = *(const float4*)&Wr[(k << 6) + j0];
        #pragma unroll
        for (int mi = 0; mi < 4; ++mi) {
            float a = As[(m0 + mi) * SA + k];
            float x = Xs[(m0 + mi) * SA + k];
            o[mi][0] += a * wl.x + x * wr.x;
            o[mi][1] += a * wl.y + x * wr.y;
            o[mi][2] += a * wl.z + x * wr.z;
            o[mi][3] += a * wl.w + x * wr.w;
        }
    }

    float4 r[4];
    #pragma unroll
    for (int mi = 0; mi < 4; ++mi) {
        r[mi] = make_float4(fmaxf(o[mi][0], 0.f), fmaxf(o[mi][1], 0.f),
                            fmaxf(o[mi][2], 0.f), fmaxf(o[mi][3], 0.f));
        *(float4*)&hout[(base + m0 + mi) * D + j0] = r[mi];   // h1, relu fused
    }

    // ---- push this block's L1 edges straight from the just-computed rows ----
    const int e0 = t * CAP1;
    const int e1 = min(cur1[t], e0 + CAP1);
    if (e0 == e1) return;                            // block-uniform

    __syncthreads();                                 // all As/Xs reads done
    unsigned* Rs = (unsigned*)As;                    // overlay: TM*SB dwords
    #pragma unroll
    for (int mi = 0; mi < 4; ++mi) {
        Rs[(m0 + mi) * SB + (j0 >> 1)]     = bf16rne(r[mi].x) | (bf16rne(r[mi].y) << 16);
        Rs[(m0 + mi) * SB + (j0 >> 1) + 1] = bf16rne(r[mi].z) | (bf16rne(r[mi].w) << 16);
    }
    __syncthreads();

    const int lane = tid & 63;
    const int w    = tid >> 6;
    const int l5   = lane & 31;
    const int hi   = lane >> 5;
    const int chunk = ((e1 - e0) + 3) >> 2;
    int e = e0 + w * chunk;
    const int ee = min(e + chunk, e1);

    for (; e + 64 <= ee; e += 64) {
        int pv = esp1[e + lane];
        #pragma unroll
        for (int u = 0; u < 32; ++u) {
            int p = __shfl(pv, (u << 1) + hi);
            unsigned v = Rs[(p & 63) * SB + l5];
            __builtin_amdgcn_global_atomic_fadd_v2bf16(
                (sbf2*)&aggbB[((p >> 6) << 5) + l5], *(sbf2*)&v);
        }
    }
    for (; e < ee; ++e) {
        int p = esp1[e];
        if (!hi) {
            unsigned v = Rs[(p & 63) * SB + l5];
            __builtin_amdgcn_global_atomic_fadd_v2bf16(
                (sbf2*)&aggbB[((p >> 6) << 5) + l5], *(sbf2*)&v);
        }
    }
}

// ---------------- finish on compacted list (layer 1, reads aggbB) ----------------

__global__ __launch_bounds__(256, 4) void sage_finish_sel(
    const float* __restrict__ hin, const unsigned* __restrict__ aggb,
    const int* __restrict__ indeg, const int* __restrict__ list,
    const int* __restrict__ pcount, float* __restrict__ hout,
    const float* __restrict__ Wl, const float* __restrict__ bl,
    const float* __restrict__ Wr)
{
    __shared__ float As[TM * SA];
    __shared__ float Xs[TM * SA];
    __shared__ float invs[TM];
    __shared__ int   nid[TM];

    const int cntv = *pcount;
    const int base = blockIdx.x * TM;
    if (base >= cntv) return;

    const int tid = threadIdx.x;
    if (tid < TM) {
        int n = (base + tid < cntv) ? list[base + tid] : -1;
        nid[tid]  = n;
        invs[tid] = (n >= 0) ? 1.0f / (float)max(indeg[n], 1) : 0.f;
    }
    __syncthreads();
    for (int idx = tid; idx < TM * 32; idx += 256) {
        int m = idx >> 5, k2 = idx & 31;
        int n = nid[m];
        if (n >= 0) {
            unsigned v = aggb[(n << 5) + k2];
            As[m * SA + (k2 << 1)]     = __uint_as_float(v << 16) * invs[m];
            As[m * SA + (k2 << 1) + 1] = __uint_as_float(v & 0xffff0000u) * invs[m];
        } else {
            As[m * SA + (k2 << 1)]     = 0.f;
            As[m * SA + (k2 << 1) + 1] = 0.f;
        }
    }
    for (int idx = tid; idx < TM * D; idx += 256) {
        int m = idx >> 6, k = idx & 63;
        int n = nid[m];
        Xs[m * SA + k] = (n >= 0) ? hin[n * D + k] : 0.f;
    }
    __syncthreads();

    const int j0 = (tid & 15) << 2;
    const int m0 = (tid >> 4) << 2;
    float o[4][4];
    float4 b4 = *(const float4*)&bl[j0];
    #pragma unroll
    for (int mi = 0; mi < 4; ++mi) {
        o[mi][0] = b4.x; o[mi][1] = b4.y; o[mi][2] = b4.z; o[mi][3] = b4.w;
    }
    #pragma unroll 8
    for (int k = 0; k < D; ++k) {
        float4 wl = *(const float4*)&Wl[(k << 6) + j0];
        float4 wr = *(const float4*)&Wr[(k << 6) + j0];
        #pragma unroll
        for (int mi = 0; mi < 4; ++mi) {
            float a = As[(m0 + mi) * SA + k];
            float x = Xs[(m0 + mi) * SA + k];
            o[mi][0] += a * wl.x + x * wr.x;
            o[mi][1] += a * wl.y + x * wr.y;
            o[mi][2] += a * wl.z + x * wr.z;
            o[mi][3] += a * wl.w + x * wr.w;
        }
    }
    #pragma unroll
    for (int mi = 0; mi < 4; ++mi) {
        int n = nid[m0 + mi];
        if (n >= 0) {
            float4 r = make_float4(fmaxf(o[mi][0], 0.f), fmaxf(o[mi][1], 0.f),
                                   fmaxf(o[mi][2], 0.f), fmaxf(o[mi][3], 0.f));
            *(float4*)&hout[n * D + j0] = r;
        }
    }
}

// ---------------- final layer GEMM on the 256 selected nodes (exact f32 agg) --------

__global__ __launch_bounds__(256, 3) void final_gemm_sel(
    const float* __restrict__ hin, const float* __restrict__ agg,
    const int* __restrict__ indeg, const int* __restrict__ fidx,
    const float* __restrict__ Wl, const float* __restrict__ bl,
    const float* __restrict__ Wr, float* __restrict__ out)
{
    __shared__ float As[TM * SA];
    __shared__ float Xs[TM * SA];
    __shared__ int   nid[TM];
    __shared__ float invs[TM];

    const int tid  = threadIdx.x;
    const int base = blockIdx.x * TM;

    if (tid < TM) {
        int n = fidx[base + tid];
        nid[tid]  = n;
        invs[tid] = 1.0f / (float)max(indeg[n], 1);
    }
    __syncthreads();
    for (int idx = tid; idx < TM * D; idx += 256) {
        int m = idx >> 6, k = idx & 63;
        int n = nid[m];
        As[m * SA + k] = agg[n * D + k] * invs[m];
        Xs[m * SA + k] = hin[n * D + k];
    }
    __syncthreads();

    const int j0 = (tid & 15) << 2;
    const int m0 = (tid >> 4) << 2;
    float o[4][4];
    float4 b4 = *(const float4*)&bl[j0];
    #pragma unroll
    for (int mi = 0; mi < 4; ++mi) {
        o[mi][0] = b4.x; o[mi][1] = b4.y; o[mi][2] = b4.z; o[mi][3] = b4.w;
    }
    #pragma unroll 8
    for (int k = 0; k < D; ++k) {
        float4 wl = *(const float4*)&Wl[(k << 6) + j0];
        float4 wr = *(const float4*)&Wr[(k << 6) + j0];
        #pragma unroll
        for (int mi = 0; mi < 4; ++mi) {
            float a = As[(m0 + mi) * SA + k];
            float x = Xs[(m0 + mi) * SA + k];
            o[mi][0] += a * wl.x + x * wr.x;
            o[mi][1] += a * wl.y + x * wr.y;
            o[mi][2] += a * wl.z + x * wr.z;
            o[mi][3] += a * wl.w + x * wr.w;
        }
    }
    #pragma unroll
    for (int mi = 0; mi < 4; ++mi) {
        float4 r = make_float4(o[mi][0], o[mi][1], o[mi][2], o[mi][3]);
        *(float4*)&out[(base + m0 + mi) * D + j0] = r;
    }
}

// ---------------- launch ----------------

extern "C" void kernel_launch(void* const* d_in, const int* in_sizes, int n_in,
                              void* d_out, int out_size, void* d_ws, size_t ws_size,
                              hipStream_t stream)
{
    const float* x     = (const float*)d_in[0];
    const int*   ei    = (const int*)d_in[1];
    const int*   batch = (const int*)d_in[2];
    const float* Wl0 = (const float*)d_in[3];
    const float* bl0 = (const float*)d_in[4];
    const float* Wr0 = (const float*)d_in[5];
    const float* Wl1 = (const float*)d_in[6];
    const float* bl1 = (const float*)d_in[7];
    const float* Wr1 = (const float*)d_in[8];
    const float* Wl2 = (const float*)d_in[9];
    const float* bl2 = (const float*)d_in[10];
    const float* Wr2 = (const float*)d_in[11];
    float* out = (float*)d_out;

    const int* src = ei;             // edge_index[0]
    const int* dst = ei + N_EDGES;   // edge_index[1]

    char* ws = (char*)d_ws;
    size_t off = 0;
    auto alloc = [&](size_t bytes) -> void* {
        void* p = ws + off;
        off = (off + bytes + 255) & ~(size_t)255;
        return p;
    };
    // ---- contiguous zero region (one hipMemsetAsync) ----
    char* zb = ws;
    unsigned* aggbA = (unsigned*)alloc((size_t)N_NODES * 32 * sizeof(unsigned)); // L0 agg
    unsigned* aggbB = (unsigned*)alloc((size_t)N_NODES * 32 * sizeof(unsigned)); // L1 agg
    unsigned* bms   = (unsigned*)alloc((size_t)3 * BMW * sizeof(unsigned));
    int*      indeg = (int*)alloc(N_NODES * sizeof(int));
    int*      n01   = (int*)alloc(64 * sizeof(int));
    size_t zbytes = off;
    // ---- non-zeroed ----
    int*      cur0  = (int*)alloc(NBLK * sizeof(int));
    int*      cur1  = (int*)alloc(NBLK * sizeof(int));
    int*      cur2  = (int*)alloc(NBLK * sizeof(int));
    int*      fidx  = (int*)alloc(NG * sizeof(int));
    int*      list1 = (int*)alloc(N_NODES * sizeof(int));
    int*      esp0  = (int*)alloc((size_t)NBLK * CAP0 * sizeof(int));
    int*      esp1  = (int*)alloc((size_t)NBLK * CAP1 * sizeof(int));
    int*      esp2  = (int*)alloc((size_t)NBLK * CAP2 * sizeof(int));
    float*    aggf  = (float*)alloc((size_t)N_NODES * D * sizeof(float));        // layer-2 exact
    float*    h1    = (float*)alloc((size_t)N_NODES * D * sizeof(float));
    float*    h2    = (float*)alloc((size_t)N_NODES * D * sizeof(float));
    unsigned* bm0 = bms;
    unsigned* bm1 = bms + BMW;
    unsigned* bm2 = bms + 2 * BMW;
    int* n1 = n01 + 1;
    (void)ws_size; (void)in_sizes; (void)n_in; (void)out_size;

    const int EB = (N_EDGES + 255) / 256;   // 5120

    hipMemsetAsync(zb, 0, zbytes, stream);  // aggbA|aggbB|bms|indeg|n01

    ff_mark<<<NB, 256, 0, stream>>>(batch, fidx, bm2, bm1, aggf, cur0, cur1, cur2);
    mark_srcs_bm<<<EB, 256, 0, stream>>>(src, dst, bm2, bm1, (const unsigned*)nullptr);
    mark_srcs_bm<<<EB, 256, 0, stream>>>(src, dst, bm1, bm0, bm1);
    build<<<NB, 256, 0, stream>>>(src, dst, bm0, bm1, bm2, cur0, cur1, cur2,
                                  esp0, esp1, esp2, indeg, list1, n1);

    // layer 0 push -> aggbA
    sage_push_bf<<<NBLK, 256, 0, stream>>>(x, cur0, esp0, aggbA, CAP0);
    // fused: dense finish L0 (reads aggbA) + push L1 (into aggbB)
    finish_dense_push1<<<NBLK, 256, 0, stream>>>(x, aggbA, indeg, h1, Wl0, bl0, Wr0,
                                                 cur1, esp1, aggbB);
    // layer 1 finish (reads aggbB)
    sage_finish_sel<<<NBLK, 256, 0, stream>>>(h1, aggbB, indeg, list1, n1,
                                              h2, Wl1, bl1, Wr1);
    // layer 2: exact f32 push into the 256 output rows + output GEMM
    sage_push_f32<<<NBLK, 256, 0, stream>>>(h2, cur2, esp2, aggf, CAP2);
    final_gemm_sel<<<NG / TM, 256, 0, stream>>>(h2, aggf, indeg, fidx, Wl2, bl2, Wr2, out);
}